// Round 14
// baseline (203.757 us; speedup 1.0000x reference)
//
#include <hip/hip_runtime.h>

// CapsuleFC: B=64, N=128, A=64, M=128, D=64
// out = [ncv (B*M*D) | na (B*M) | qk (B*N*M)], fp32
// R14: scale producer waves. 1024-thr blocks (16 waves): 8 producers
// (pure DMA streamers, 4 rows/tile each, 4-tile ring, 16 DMAs in flight,
// steady vmcnt(12)) + 8 consumers (identical verified MFMA math).
typedef __attribute__((ext_vector_type(8))) short bf16x8;
typedef __attribute__((ext_vector_type(4))) float f32x4;

constexpr int Bq = 64, Nq = 128, Aq = 64, Mq = 128, Dq = 64;
constexpr int MD = Mq * Dq;    // 8192
constexpr int NM = Nq * Mq;    // 16384
constexpr int NA = Nq * Aq;    // 8192
constexpr int NCV_SZ = Bq * MD;   // 524288
constexpr int NA_SZ  = Bq * Mq;   // 8192
constexpr float SCALE = 0.125f;   // 1/sqrt(64)

__device__ __forceinline__ unsigned short f2b(float f) {  // fp32 -> bf16 RNE
  unsigned u = __float_as_uint(f);
  return (unsigned short)((u + 0x7fffu + ((u >> 16) & 1u)) >> 16);
}
__device__ __forceinline__ unsigned cvt2(float lo, float hi) {
  return ((unsigned)f2b(hi) << 16) | (unsigned)f2b(lo);
}
__device__ __forceinline__ bf16x8 pack8(const float* v) {
  union { unsigned u[4]; bf16x8 b; } x;
  x.u[0] = cvt2(v[0], v[1]); x.u[1] = cvt2(v[2], v[3]);
  x.u[2] = cvt2(v[4], v[5]); x.u[3] = cvt2(v[6], v[7]);
  return x.b;
}
__device__ __forceinline__ void dma16(const float* g, float* l) {
  __builtin_amdgcn_global_load_lds(
      (const __attribute__((address_space(1))) unsigned*)g,
      (__attribute__((address_space(3))) unsigned*)l, 16, 0, 0);
}

// ---------------- init: ncv = 0, na = 1 ----------------
__global__ __launch_bounds__(256) void k0_init(float* __restrict__ out) {
  int i = blockIdx.x * 256 + threadIdx.x;
  if (i < NCV_SZ) out[i] = 0.0f;
  else if (i < NCV_SZ + NA_SZ) out[i] = 1.0f;
}

// ---------------- K1: logits, 8P+8C producer/consumer MFMA ----------------
// grid (mc=32, ns=8), block 1024. 16 n's / 32 half-tile phases, descending.
__global__ __launch_bounds__(1024) void k1_logits(
    const float* __restrict__ input, const float* __restrict__ ncvin,
    const float* __restrict__ wgt, float* __restrict__ logits) {
  const int mc = blockIdx.x;
  const int n0 = blockIdx.y * 16;
  const int t = threadIdx.x;
  const int w = t >> 6, l = t & 63;
  __shared__ float Wf[4][32 * 256];   // 128 KB, 4-tile ring

  if (w >= 8) {
    // ======== PRODUCER (waves 8..15): pure DMA streamer, 4 rows/tile ========
    const int pw = w - 8;
    auto stageT = [&](int h) {        // descending walk: hh = 31-h
      const int hh = 31 - h;
      const int nn = n0 + (hh >> 1);
      const int ks = (hh & 1) * 32;
      float* dst = &Wf[h & 3][0];
#pragma unroll
      for (int rr = 0; rr < 4; ++rr) {
        const int al = pw * 4 + rr;
        const char* gs = (const char*)(wgt + (size_t)(nn * Aq + ks + al) * MD + mc * 256)
                         + ((l * 16) ^ (((al >> 3) & 1) << 6));
        dma16((const float*)gs, dst + al * 256);
      }
    };
    stageT(0); stageT(1); stageT(2); stageT(3);   // 16 DMAs in flight
    for (int h = 0; h < 32; ++h) {
      if (h <= 28)      asm volatile("s_waitcnt vmcnt(12)" ::: "memory");
      else if (h == 29) asm volatile("s_waitcnt vmcnt(8)"  ::: "memory");
      else if (h == 30) asm volatile("s_waitcnt vmcnt(4)"  ::: "memory");
      else              asm volatile("s_waitcnt vmcnt(0)"  ::: "memory");
      __builtin_amdgcn_s_barrier();   // A: tile h landed
      __builtin_amdgcn_s_barrier();   // B: consumers done reading buf[h&3]
      if (h + 4 < 32) stageT(h + 4);  // refill ring
    }
  } else {
    // ======== CONSUMER (waves 0..7): MFMA + epilogue ========
    const int wv_m = w & 3, wv_b = w >> 2;
    const int lr = l & 15, g = l >> 4;
    const int m = mc * 4 + wv_m;

    float cnv[2][4][4];               // ncvin fragment (own counter, preloaded)
#pragma unroll
    for (int i = 0; i < 2; ++i)
#pragma unroll
      for (int j = 0; j < 4; ++j)
#pragma unroll
        for (int r = 0; r < 4; ++r)
          cnv[i][j][r] = ncvin[(size_t)(32 * wv_b + 16 * i + 4 * g + r) * MD + m * Dq + 16 * j + lr];

    auto loadAv = [&](int h, float (&av)[2][8]) {
      if (h > 31) return;
      const int hh = 31 - h;
      const int nn = n0 + (hh >> 1);
      const int ks = (hh & 1) * 32;
#pragma unroll
      for (int i = 0; i < 2; ++i) {
        const float* ap = input + (size_t)(32 * wv_b + 16 * i + lr) * NA + nn * Aq + ks + g * 8;
        *(float4*)&av[i][0] = *(const float4*)ap;
        *(float4*)&av[i][4] = *(const float4*)(ap + 4);
      }
    };
    auto mfmaPhase = [&](int h, float (&av)[2][8], f32x4 (&acc)[2][4]) {
      bf16x8 af[2];
#pragma unroll
      for (int i = 0; i < 2; ++i) af[i] = pack8(av[i]);
      const float* bufp = &Wf[h & 3][0];
#pragma unroll
      for (int j = 0; j < 4; ++j) {
        const int cx = (64 * wv_m + 16 * j + lr) ^ ((g & 1) << 4);
        float bv[8];
#pragma unroll
        for (int e = 0; e < 8; ++e) bv[e] = bufp[(g * 8 + e) * 256 + cx];
        bf16x8 bf = pack8(bv);
#pragma unroll
        for (int i = 0; i < 2; ++i)
          acc[i][j] = __builtin_amdgcn_mfma_f32_16x16x32_bf16(af[i], bf, acc[i][j], 0, 0, 0);
      }
    };

    float avE[2][8], avO[2][8];
    loadAv(0, avE);
    f32x4 acc[2][4];
    for (int h = 0; h < 32; ++h) {
      __builtin_amdgcn_s_barrier();   // A: buf[h&3] ready
      if ((h & 1) == 0) {
#pragma unroll
        for (int i = 0; i < 2; ++i)
#pragma unroll
          for (int j = 0; j < 4; ++j) acc[i][j] = (f32x4)(0.0f);
        loadAv(h + 1, avO);           // prefetch next av (own counter)
        mfmaPhase(h, avE, acc);
      } else {
        loadAv(h + 1, avE);
        mfmaPhase(h, avO, acc);
        {   // epilogue for this nn (register-only + shfl + one store)
          const int nn = n0 + ((31 - h) >> 1);
          float lp[2][4];
#pragma unroll
          for (int i = 0; i < 2; ++i)
#pragma unroll
            for (int r = 0; r < 4; ++r) lp[i][r] = 0.0f;
#pragma unroll
          for (int i = 0; i < 2; ++i)
#pragma unroll
            for (int j = 0; j < 4; ++j)
#pragma unroll
              for (int r = 0; r < 4; ++r)
                lp[i][r] = fmaf(acc[i][j][r], cnv[i][j][r], lp[i][r]);
#pragma unroll
          for (int off = 1; off < 16; off <<= 1)
#pragma unroll
            for (int i = 0; i < 2; ++i)
#pragma unroll
              for (int r = 0; r < 4; ++r) lp[i][r] += __shfl_xor(lp[i][r], off);
          float ov = lp[0][0];
#pragma unroll
          for (int i = 0; i < 2; ++i)
#pragma unroll
            for (int r = 0; r < 4; ++r)
              ov = (lr == i * 4 + r) ? lp[i][r] : ov;
          if (lr < 8) {
            const int b = 32 * wv_b + 16 * (lr >> 2) + 4 * g + (lr & 3);
            logits[(size_t)b * NM + (size_t)nn * Mq + m] = SCALE * ov;
          }
        }
      }
      __builtin_amdgcn_s_barrier();   // B: done reading buf[h&3]
    }
  }
}

// ---------------- K2: softmax + act modulation + renorm (in place) ----------------
__global__ __launch_bounds__(256) void k2_softmax(
    const float* __restrict__ next_act, float* __restrict__ qk) {
  const int row  = blockIdx.x * 4 + (threadIdx.x >> 6);
  const int lane = threadIdx.x & 63;
  const int b = row >> 7;
  float* p = qk + (size_t)row * Mq;
  float x0 = p[lane], x1 = p[lane + 64];
  float mx = fmaxf(x0, x1);
#pragma unroll
  for (int off = 32; off; off >>= 1) mx = fmaxf(mx, __shfl_xor(mx, off));
  float e0 = __expf(x0 - mx), e1 = __expf(x1 - mx);
  float s = e0 + e1;
#pragma unroll
  for (int off = 32; off; off >>= 1) s += __shfl_xor(s, off);
  float a0 = next_act[b * Mq + lane], a1 = next_act[b * Mq + lane + 64];
  float t0 = (e0 / s) * a0, t1 = (e1 / s) * a1;
  float s2 = t0 + t1;
#pragma unroll
  for (int off = 32; off; off >>= 1) s2 += __shfl_xor(s2, off);
  s2 += 1e-10f;
  p[lane]      = t0 / s2;
  p[lane + 64] = t1 / s2;
}

// ---------------- K3: aggregation, 8P+8C producer/consumer (ascending) ----------------
__global__ __launch_bounds__(1024) void k3_aggregate(
    const float* __restrict__ input, const float* __restrict__ cur_act,
    const float* __restrict__ wgt, const float* __restrict__ qk,
    float* __restrict__ ncv) {
  const int mc = blockIdx.x;
  const int n0 = blockIdx.y * 16;
  const int t = threadIdx.x;
  const int w = t >> 6, l = t & 63;
  __shared__ float Wf[4][32 * 256];   // 128 KB
  __shared__ float zl[16][4][64];     // 16 KB

  // all threads stage z = qk*cur_act (1024 entries, 1 each), then split roles
  {
    const int b = t >> 4, nn = t & 15;
    float4 q4 = *(const float4*)&qk[(size_t)b * NM + (size_t)(n0 + nn) * Mq + mc * 4];
    float ca = cur_act[b * Nq + n0 + nn];
    zl[nn][0][b] = q4.x * ca; zl[nn][1][b] = q4.y * ca;
    zl[nn][2][b] = q4.z * ca; zl[nn][3][b] = q4.w * ca;
  }
  __syncthreads();

  if (w >= 8) {
    // ======== PRODUCER ========
    const int pw = w - 8;
    auto stageT = [&](int h) {        // ascending walk
      const int nn = n0 + (h >> 1);
      const int ks = (h & 1) * 32;
      float* dst = &Wf[h & 3][0];
#pragma unroll
      for (int rr = 0; rr < 4; ++rr) {
        const int al = pw * 4 + rr;
        const char* gs = (const char*)(wgt + (size_t)(nn * Aq + ks + al) * MD + mc * 256)
                         + ((l * 16) ^ (((al >> 3) & 1) << 6));
        dma16((const float*)gs, dst + al * 256);
      }
    };
    stageT(0); stageT(1); stageT(2); stageT(3);
    for (int h = 0; h < 32; ++h) {
      if (h <= 28)      asm volatile("s_waitcnt vmcnt(12)" ::: "memory");
      else if (h == 29) asm volatile("s_waitcnt vmcnt(8)"  ::: "memory");
      else if (h == 30) asm volatile("s_waitcnt vmcnt(4)"  ::: "memory");
      else              asm volatile("s_waitcnt vmcnt(0)"  ::: "memory");
      __builtin_amdgcn_s_barrier();   // A
      __builtin_amdgcn_s_barrier();   // B
      if (h + 4 < 32) stageT(h + 4);
    }
  } else {
    // ======== CONSUMER ========
    const int wv_m = w & 3, wv_b = w >> 2;
    const int lr = l & 15, g = l >> 4;
    const int m = mc * 4 + wv_m;

    auto loadAv = [&](int h, float (&av)[2][8]) {
      if (h > 31) return;
      const int nn = n0 + (h >> 1);
      const int ks = (h & 1) * 32;
#pragma unroll
      for (int i = 0; i < 2; ++i) {
        const float* ap = input + (size_t)(32 * wv_b + 16 * i + lr) * NA + nn * Aq + ks + g * 8;
        *(float4*)&av[i][0] = *(const float4*)ap;
        *(float4*)&av[i][4] = *(const float4*)(ap + 4);
      }
    };
    auto mfmaPhase = [&](int h, float (&av)[2][8], float (&zr)[2], f32x4 (&acc)[2][4]) {
      bf16x8 af[2];
#pragma unroll
      for (int i = 0; i < 2; ++i) {
        float sv[8];
#pragma unroll
        for (int e = 0; e < 8; ++e) sv[e] = av[i][e] * zr[i];
        af[i] = pack8(sv);
      }
      const float* bufp = &Wf[h & 3][0];
#pragma unroll
      for (int j = 0; j < 4; ++j) {
        const int cx = (64 * wv_m + 16 * j + lr) ^ ((g & 1) << 4);
        float bv[8];
#pragma unroll
        for (int e = 0; e < 8; ++e) bv[e] = bufp[(g * 8 + e) * 256 + cx];
        bf16x8 bf = pack8(bv);
#pragma unroll
        for (int i = 0; i < 2; ++i)
          acc[i][j] = __builtin_amdgcn_mfma_f32_16x16x32_bf16(af[i], bf, acc[i][j], 0, 0, 0);
      }
    };

    float avE[2][8], avO[2][8];
    loadAv(0, avE);
    f32x4 acc[2][4];
#pragma unroll
    for (int i = 0; i < 2; ++i)
#pragma unroll
      for (int j = 0; j < 4; ++j) acc[i][j] = (f32x4)(0.0f);

    float zr[2];
    for (int h = 0; h < 32; ++h) {
      __builtin_amdgcn_s_barrier();   // A
      if ((h & 1) == 0) {
#pragma unroll
        for (int i = 0; i < 2; ++i) zr[i] = zl[h >> 1][wv_m][32 * wv_b + 16 * i + lr];
        loadAv(h + 1, avO);
        mfmaPhase(h, avE, zr, acc);
      } else {
        loadAv(h + 1, avE);
        mfmaPhase(h, avO, zr, acc);
      }
      __builtin_amdgcn_s_barrier();   // B
    }

    // epilogue: atomic partial sums over the 8 n-split blocks
#pragma unroll
    for (int i = 0; i < 2; ++i)
#pragma unroll
      for (int j = 0; j < 4; ++j) {
        const int d = 16 * j + lr;
#pragma unroll
        for (int r = 0; r < 4; ++r) {
          const int b = 32 * wv_b + 16 * i + 4 * g + r;
          atomicAdd(&ncv[(size_t)b * MD + m * Dq + d], acc[i][j][r]);
        }
      }
  }
}

extern "C" void kernel_launch(void* const* d_in, const int* in_sizes, int n_in,
                              void* d_out, int out_size, void* d_ws, size_t ws_size,
                              hipStream_t stream) {
  const float* input    = (const float*)d_in[0];
  const float* cur_act  = (const float*)d_in[1];
  const float* ncvin    = (const float*)d_in[2];
  const float* next_act = (const float*)d_in[3];
  const float* wgt      = (const float*)d_in[4];
  // d_in[5] = num_iter (unused by reference)

  float* out = (float*)d_out;
  float* ncv = out;
  float* qk  = out + NCV_SZ + NA_SZ;

  k0_init<<<(NCV_SZ + NA_SZ + 255) / 256, 256, 0, stream>>>(out);
  k1_logits<<<dim3(32, 8), 1024, 0, stream>>>(input, ncvin, wgt, qk);
  k2_softmax<<<(Bq * Nq) / 4, 256, 0, stream>>>(next_act, qk);
  k3_aggregate<<<dim3(32, 8), 1024, 0, stream>>>(input, cur_act, wgt, qk, ncv);
}

// Round 15
// 144.351 us; speedup vs baseline: 1.4115x; 1.4115x over previous
//
#include <hip/hip_runtime.h>

// CapsuleFC: B=64, N=128, A=64, M=128, D=64
// out = [ncv (B*M*D) | na (B*M) | qk (B*N*M)], fp32
// R15: ZERO steady-state barriers. 4 waves/block, each wave = its own
// producer+consumer: private 2-slot LDS ring (8KB half-tiles), own vmcnt
// discipline, full-b per-wave MFMA math (verified r5). 2 blocks/CU.
typedef __attribute__((ext_vector_type(8))) short bf16x8;
typedef __attribute__((ext_vector_type(4))) float f32x4;

constexpr int Bq = 64, Nq = 128, Aq = 64, Mq = 128, Dq = 64;
constexpr int MD = Mq * Dq;    // 8192
constexpr int NM = Nq * Mq;    // 16384
constexpr int NA = Nq * Aq;    // 8192
constexpr int NCV_SZ = Bq * MD;   // 524288
constexpr int NA_SZ  = Bq * Mq;   // 8192
constexpr float SCALE = 0.125f;   // 1/sqrt(64)

__device__ __forceinline__ unsigned short f2b(float f) {  // fp32 -> bf16 RNE
  unsigned u = __float_as_uint(f);
  return (unsigned short)((u + 0x7fffu + ((u >> 16) & 1u)) >> 16);
}
__device__ __forceinline__ unsigned cvt2(float lo, float hi) {
  return ((unsigned)f2b(hi) << 16) | (unsigned)f2b(lo);
}
__device__ __forceinline__ bf16x8 pack8(const float* v) {
  union { unsigned u[4]; bf16x8 b; } x;
  x.u[0] = cvt2(v[0], v[1]); x.u[1] = cvt2(v[2], v[3]);
  x.u[2] = cvt2(v[4], v[5]); x.u[3] = cvt2(v[6], v[7]);
  return x.b;
}
__device__ __forceinline__ void dma16(const float* g, float* l) {
  __builtin_amdgcn_global_load_lds(
      (const __attribute__((address_space(1))) unsigned*)g,
      (__attribute__((address_space(3))) unsigned*)l, 16, 0, 0);
}

// ---------------- init: ncv = 0, na = 1 ----------------
__global__ __launch_bounds__(256) void k0_init(float* __restrict__ out) {
  int i = blockIdx.x * 256 + threadIdx.x;
  if (i < NCV_SZ) out[i] = 0.0f;
  else if (i < NCV_SZ + NA_SZ) out[i] = 1.0f;
}

// Per-wave half-tile LDS layout (8 KB): LDS[r=32 rows][256 B], where
// LDS[r][c] = W[a=ks*32+r][byte c ^ (((r>>3)&1)<<6)] of the wave's m-column.
// Store side: DMA al covers rows al*4..+3, swz=(al>>1)&1 uniform per instr
// (applied to the GLOBAL source per rule #21); read side applies same XOR.

// ---------------- K1: logits, barrier-free wave-private pipeline ----------------
// grid (mc=32, ns=16), block 256 = 4 waves; wave wv: m = mc*4+wv, full b.
// 8 n's per block, 16 half-tile phases, DESCENDING walk (L3-cyclic with k3).
__global__ __launch_bounds__(256, 2) void k1_logits(
    const float* __restrict__ input, const float* __restrict__ ncvin,
    const float* __restrict__ wgt, float* __restrict__ logits) {
  const int mc = blockIdx.x;
  const int n0 = blockIdx.y * 8;
  const int t = threadIdx.x;
  const int wv = t >> 6, l = t & 63;
  const int lr = l & 15, g = l >> 4;
  const int m = mc * 4 + wv;
  __shared__ float Wr[4][2][2048];   // 4 waves x 2 slots x 8 KB = 64 KB

  // preload ncvin fragment (epilogue is register-only afterwards)
  float cnv[4][4][4];
#pragma unroll
  for (int i = 0; i < 4; ++i)
#pragma unroll
    for (int j = 0; j < 4; ++j)
#pragma unroll
      for (int r = 0; r < 4; ++r)
        cnv[i][j][r] = ncvin[(size_t)(16 * i + 4 * g + r) * MD + m * Dq + 16 * j + lr];

  auto stageH = [&](int h) {         // stage half-tile h into slot h&1
    if (h > 15) return;
    const int hh = 15 - h;
    const int nn = n0 + (hh >> 1), ks = hh & 1;
    char* dst = (char*)&Wr[wv][h & 1][0];
    const char* wb = (const char*)wgt;
#pragma unroll
    for (int al = 0; al < 8; ++al) {
      const int swz = (al >> 1) & 1;
      const char* gs = wb + (size_t)(nn * 64 + ks * 32 + al * 4 + g) * 32768
                       + (size_t)m * 256 + ((lr * 16) ^ (swz << 6));
      dma16((const float*)gs, (float*)(dst + al * 1024));
    }
  };
  auto loadAv = [&](int h, float (&av)[4][8]) {
    const int hh = 15 - h;
    const int nn = n0 + (hh >> 1), ks = hh & 1;
#pragma unroll
    for (int i = 0; i < 4; ++i) {
      const float* ap = input + (size_t)(16 * i + lr) * NA + nn * Aq + ks * 32 + g * 8;
      *(float4*)&av[i][0] = *(const float4*)ap;
      *(float4*)&av[i][4] = *(const float4*)(ap + 4);
    }
  };

  stageH(0);
  f32x4 acc[4][4];
  for (int h = 0; h < 16; ++h) {
    float av[4][8];
    loadAv(h, av);                   // av BEFORE next DMAs (counter discipline)
    __builtin_amdgcn_sched_barrier(0);
    stageH(h + 1);
    __builtin_amdgcn_sched_barrier(0);
    // retire dma(h) (+any old store); keep av(h)+dma(h+1) in flight
    if (h < 15) asm volatile("s_waitcnt vmcnt(16)" ::: "memory");
    else        asm volatile("s_waitcnt vmcnt(8)"  ::: "memory");
    __builtin_amdgcn_sched_barrier(0);

    if ((h & 1) == 0) {
#pragma unroll
      for (int i = 0; i < 4; ++i)
#pragma unroll
        for (int j = 0; j < 4; ++j) acc[i][j] = (f32x4)(0.0f);
    }

    bf16x8 af[4];
#pragma unroll
    for (int i = 0; i < 4; ++i) af[i] = pack8(av[i]);   // compiler waits av only

    const char* lb = (const char*)&Wr[wv][h & 1][0];
#pragma unroll
    for (int j = 0; j < 4; ++j) {
      float bv[8];
#pragma unroll
      for (int e = 0; e < 8; ++e)
        bv[e] = *(const float*)(lb + (g * 8 + e) * 256 + (((16 * j + lr) * 4) ^ ((g & 1) << 6)));
      bf16x8 bf = pack8(bv);
#pragma unroll
      for (int i = 0; i < 4; ++i)
        acc[i][j] = __builtin_amdgcn_mfma_f32_16x16x32_bf16(af[i], bf, acc[i][j], 0, 0, 0);
    }

    if (h & 1) {                     // epilogue for nn (register-only + shfl + 1 store)
      const int nn = n0 + ((15 - h) >> 1);
      float lp[4][4];
#pragma unroll
      for (int i = 0; i < 4; ++i)
#pragma unroll
        for (int r = 0; r < 4; ++r) lp[i][r] = 0.0f;
#pragma unroll
      for (int i = 0; i < 4; ++i)
#pragma unroll
        for (int j = 0; j < 4; ++j)
#pragma unroll
          for (int r = 0; r < 4; ++r)
            lp[i][r] = fmaf(acc[i][j][r], cnv[i][j][r], lp[i][r]);
#pragma unroll
      for (int off = 1; off < 16; off <<= 1)
#pragma unroll
        for (int i = 0; i < 4; ++i)
#pragma unroll
          for (int r = 0; r < 4; ++r) lp[i][r] += __shfl_xor(lp[i][r], off);
      float ov = lp[0][0];
#pragma unroll
      for (int i = 0; i < 4; ++i)
#pragma unroll
        for (int r = 0; r < 4; ++r)
          ov = (lr == i * 4 + r) ? lp[i][r] : ov;
      const int b = 16 * (lr >> 2) + 4 * g + (lr & 3);
      logits[(size_t)b * NM + (size_t)nn * Mq + m] = SCALE * ov;
    }
  }
}

// ---------------- K2: softmax + act modulation + renorm (in place) ----------------
__global__ __launch_bounds__(256) void k2_softmax(
    const float* __restrict__ next_act, float* __restrict__ qk) {
  const int row  = blockIdx.x * 4 + (threadIdx.x >> 6);
  const int lane = threadIdx.x & 63;
  const int b = row >> 7;
  float* p = qk + (size_t)row * Mq;
  float x0 = p[lane], x1 = p[lane + 64];
  float mx = fmaxf(x0, x1);
#pragma unroll
  for (int off = 32; off; off >>= 1) mx = fmaxf(mx, __shfl_xor(mx, off));
  float e0 = __expf(x0 - mx), e1 = __expf(x1 - mx);
  float s = e0 + e1;
#pragma unroll
  for (int off = 32; off; off >>= 1) s += __shfl_xor(s, off);
  float a0 = next_act[b * Mq + lane], a1 = next_act[b * Mq + lane + 64];
  float t0 = (e0 / s) * a0, t1 = (e1 / s) * a1;
  float s2 = t0 + t1;
#pragma unroll
  for (int off = 32; off; off >>= 1) s2 += __shfl_xor(s2, off);
  s2 += 1e-10f;
  p[lane]      = t0 / s2;
  p[lane + 64] = t1 / s2;
}

// ---------------- K3: aggregation, barrier-free wave-private (ascending) ----------------
__global__ __launch_bounds__(256, 2) void k3_aggregate(
    const float* __restrict__ input, const float* __restrict__ cur_act,
    const float* __restrict__ wgt, const float* __restrict__ qk,
    float* __restrict__ ncv) {
  const int mc = blockIdx.x;
  const int n0 = blockIdx.y * 8;
  const int t = threadIdx.x;
  const int wv = t >> 6, l = t & 63;
  const int lr = l & 15, g = l >> 4;
  const int m = mc * 4 + wv;
  __shared__ float Wr[4][2][2048];   // 64 KB
  __shared__ float zl[8][4][64];     // 8 KB

  // pre-stage z = qk*cur_act once (the ONLY barrier, before any DMA)
#pragma unroll
  for (int p = 0; p < 2; ++p) {
    const int idx = t + p * 256;
    const int b = idx >> 3, nn = idx & 7;
    float4 q4 = *(const float4*)&qk[(size_t)b * NM + (size_t)(n0 + nn) * Mq + mc * 4];
    float ca = cur_act[b * Nq + n0 + nn];
    zl[nn][0][b] = q4.x * ca; zl[nn][1][b] = q4.y * ca;
    zl[nn][2][b] = q4.z * ca; zl[nn][3][b] = q4.w * ca;
  }
  __syncthreads();

  auto stageH = [&](int h) {         // ascending walk
    if (h > 15) return;
    const int nn = n0 + (h >> 1), ks = h & 1;
    char* dst = (char*)&Wr[wv][h & 1][0];
    const char* wb = (const char*)wgt;
#pragma unroll
    for (int al = 0; al < 8; ++al) {
      const int swz = (al >> 1) & 1;
      const char* gs = wb + (size_t)(nn * 64 + ks * 32 + al * 4 + g) * 32768
                       + (size_t)m * 256 + ((lr * 16) ^ (swz << 6));
      dma16((const float*)gs, (float*)(dst + al * 1024));
    }
  };
  auto loadAv = [&](int h, float (&av)[4][8]) {
    const int nn = n0 + (h >> 1), ks = h & 1;
#pragma unroll
    for (int i = 0; i < 4; ++i) {
      const float* ap = input + (size_t)(16 * i + lr) * NA + nn * Aq + ks * 32 + g * 8;
      *(float4*)&av[i][0] = *(const float4*)ap;
      *(float4*)&av[i][4] = *(const float4*)(ap + 4);
    }
  };

  stageH(0);
  f32x4 acc[4][4];
#pragma unroll
  for (int i = 0; i < 4; ++i)
#pragma unroll
    for (int j = 0; j < 4; ++j) acc[i][j] = (f32x4)(0.0f);

  float zr[4];
  for (int h = 0; h < 16; ++h) {
    float av[4][8];
    loadAv(h, av);
    __builtin_amdgcn_sched_barrier(0);
    stageH(h + 1);
    __builtin_amdgcn_sched_barrier(0);
    if (h < 15) asm volatile("s_waitcnt vmcnt(16)" ::: "memory");
    else        asm volatile("s_waitcnt vmcnt(8)"  ::: "memory");
    __builtin_amdgcn_sched_barrier(0);

    if ((h & 1) == 0) {
#pragma unroll
      for (int i = 0; i < 4; ++i) zr[i] = zl[h >> 1][wv][16 * i + lr];
    }

    bf16x8 af[4];
#pragma unroll
    for (int i = 0; i < 4; ++i) {
      float sv[8];
#pragma unroll
      for (int e = 0; e < 8; ++e) sv[e] = av[i][e] * zr[i];
      af[i] = pack8(sv);
    }

    const char* lb = (const char*)&Wr[wv][h & 1][0];
#pragma unroll
    for (int j = 0; j < 4; ++j) {
      float bv[8];
#pragma unroll
      for (int e = 0; e < 8; ++e)
        bv[e] = *(const float*)(lb + (g * 8 + e) * 256 + (((16 * j + lr) * 4) ^ ((g & 1) << 6)));
      bf16x8 bf = pack8(bv);
#pragma unroll
      for (int i = 0; i < 4; ++i)
        acc[i][j] = __builtin_amdgcn_mfma_f32_16x16x32_bf16(af[i], bf, acc[i][j], 0, 0, 0);
    }
  }

  // epilogue: atomic partial sums over the 16 n-split blocks
#pragma unroll
  for (int i = 0; i < 4; ++i)
#pragma unroll
    for (int j = 0; j < 4; ++j) {
      const int d = 16 * j + lr;
#pragma unroll
      for (int r = 0; r < 4; ++r) {
        const int b = 16 * i + 4 * g + r;
        atomicAdd(&ncv[(size_t)b * MD + m * Dq + d], acc[i][j][r]);
      }
    }
}

extern "C" void kernel_launch(void* const* d_in, const int* in_sizes, int n_in,
                              void* d_out, int out_size, void* d_ws, size_t ws_size,
                              hipStream_t stream) {
  const float* input    = (const float*)d_in[0];
  const float* cur_act  = (const float*)d_in[1];
  const float* ncvin    = (const float*)d_in[2];
  const float* next_act = (const float*)d_in[3];
  const float* wgt      = (const float*)d_in[4];
  // d_in[5] = num_iter (unused by reference)

  float* out = (float*)d_out;
  float* ncv = out;
  float* qk  = out + NCV_SZ + NA_SZ;

  k0_init<<<(NCV_SZ + NA_SZ + 255) / 256, 256, 0, stream>>>(out);
  k1_logits<<<dim3(32, 16), 256, 0, stream>>>(input, ncvin, wgt, qk);
  k2_softmax<<<(Bq * Nq) / 4, 256, 0, stream>>>(next_act, qk);
  k3_aggregate<<<dim3(32, 16), 256, 0, stream>>>(input, cur_act, wgt, qk, ncv);
}